// Round 7
// baseline (258.684 us; speedup 1.0000x reference)
//
#include <hip/hip_runtime.h>
#include <math.h>

// Problem constants (fixed by the reference): ip (8, 256, 128, 128) fp32.
#define NB   8
#define NC   256
#define NHW  (128 * 128)

// Out[c,p] = sum_k M[c,k] X[k,p], M = 256x256 DCT-III matrix.
// Symmetry: M[255-c][k] = (-1)^k M[c][k] -> store rows c=0..127 only (bf16);
// mirror half via sign-flipped odd-k M fragments (XOR bit 31 per dword).
//
// Round-6 changes vs r5 (theory: HBM WRITE path is the binding resource —
// dur tracked WRITE_SIZE/1.55 TB/s across r0/r1/r2/r5):
//  1. SWAPPED-operand MFMA: D = mfma(A=Xfrag[p][k], B=Mfrag[c][k]) -> D rows=p,
//     cols=c; each lane's 4 acc regs = 4 consecutive p at one c -> epilogue is
//     8 global_store_dwordx4/lane (was 32 scalar dwords). Frag LDS reads are
//     unchanged 16-B [row][8k] chunks for both operands.
//  2. XCD-bijective swizzle: work = (bid%8)*512 + bid/8 -> each XCD owns one
//     batch, sweeps p-tiles sequentially -> page-friendly per-XCD write sweep.
//  3. Block = 256 thr, stored-c tile 64, p tile 64, BK=64 -> LDS 32 KB,
//     __launch_bounds__(256,5) -> 5 staggered blocks/CU.

#define BK 64
#define NITER (NC / BK)       // 4
#define ABUF 8192             // A buffers at 0, 8192      (64 rows x 128 B)
#define XLDS 16384            // X buffers at 16384, 24576 (64 rows x 128 B)
#define XBUF 8192

typedef __attribute__((ext_vector_type(4))) float f32x4;
typedef __attribute__((ext_vector_type(8))) short bf16x8;
typedef __attribute__((ext_vector_type(4))) unsigned int u32x4;

__device__ __forceinline__ unsigned short f2bf(float f) {
    unsigned u = __builtin_bit_cast(unsigned, f);
    u += 0x7fffu + ((u >> 16) & 1u);
    return (unsigned short)(u >> 16);
}

__device__ __forceinline__ unsigned pack2bf(float a, float b) {
    unsigned lo = __builtin_bit_cast(unsigned, a);
    lo += 0x7fffu + ((lo >> 16) & 1u);
    unsigned hi = __builtin_bit_cast(unsigned, b);
    hi += 0x7fffu + ((hi >> 16) & 1u);
    return (lo >> 16) | (hi & 0xffff0000u);
}

// Flip sign of odd-k bf16 elements: dword = (even k | odd k << 16) -> XOR bit 31.
__device__ __forceinline__ bf16x8 flip_odd(bf16x8 b) {
    u32x4 u = __builtin_bit_cast(u32x4, b);
    u ^= (u32x4){0x80000000u, 0x80000000u, 0x80000000u, 0x80000000u};
    return __builtin_bit_cast(bf16x8, u);
}

// DCT-III coefficients, rows c = 0..127 only. M[c][k] = (k==0)?1:2cos(pi*k*(2c+1)/512).
__global__ void coef_kernel(unsigned short* __restrict__ coef) {
    int idx = blockIdx.x * 256 + threadIdx.x;     // 0..32767
    int c = idx >> 8;
    int k = idx & 255;
    int t = (k * (2 * c + 1)) & 1023;
    float v = (k == 0) ? 1.0f : 2.0f * cosf((float)t * (float)(M_PI / 512.0));
    coef[idx] = f2bf(v);
}

__device__ __forceinline__ void gload_lds16(const void* g, void* l) {
    __builtin_amdgcn_global_load_lds(
        (const __attribute__((address_space(1))) unsigned int*)g,
        (__attribute__((address_space(3))) unsigned int*)l,
        16, 0, 0);
}

// LDS rows are 128 B (64 bf16 = one BK window), 8 16-B slots/row.
// Logical slot s of row r stored at s ^ (r & 7) -> all b128 ops <=2-way (free).

__global__ __launch_bounds__(256, 5)
void dct_gemm(const float* __restrict__ X, const unsigned short* __restrict__ Mcoef,
              float* __restrict__ Out) {
    __shared__ __align__(16) unsigned char lds[32768];

    const int tid  = threadIdx.x;
    const int lane = tid & 63;
    const int wave = tid >> 6;
    const int m16  = lane & 15;
    const int quad = lane >> 4;
    const int pw   = wave & 1;        // p-half (32)
    const int cw   = wave >> 1;       // 0..1: stored-c half of this block's 64

    // XCD-bijective swizzle: XCD x = bid%8 gets work chunk x*512.. -> one batch.
    const int w  = (blockIdx.x & 7) * 512 + (blockIdx.x >> 3);
    const int b  = w >> 9;            // batch 0..7 == XCD id
    const int ct = (w >> 8) & 1;      // stored-c tile: rows ct*64..+63
    const int pt = w & 255;           // p-tile: cols pt*64..+63

    const int p0 = pt * 64;
    const size_t base = (size_t)b * (NC * NHW);
    const float* Xg = X + base;
    float* Ob = Out + base + p0;

    // ---- A staging (global_load_lds, linear dest, pre-swizzled source) ----
    // instr i: dest L = i*4096 + tid*16 -> row = i*32 + tid/8, dslot = tid&7.
    const int aRow  = tid >> 3;                      // 0..31
    const int aSlot = (tid & 7) ^ (aRow & 7);
    const unsigned short* aS = Mcoef + (ct * 64 + aRow) * NC + aSlot * 8;
    const int aDst = tid * 16;

    // ---- X staging: p = tid&63, k-groups kg and kg+4 (8 k each) ----
    const int sp = tid & 63;
    const int kg = tid >> 6;                         // 0..3
    const float* xS = Xg + (size_t)(kg * 8) * NHW + p0 + sp;
    const int xW0 = XLDS + sp * 128 + (((kg    ) ^ (sp & 7)) << 4);
    const int xW1 = XLDS + sp * 128 + (((kg + 4) ^ (sp & 7)) << 4);

    f32x4 acc[2][2][2];
#pragma unroll
    for (int i = 0; i < 2; i++)
#pragma unroll
        for (int j = 0; j < 2; j++)
#pragma unroll
            for (int h = 0; h < 2; h++) acc[i][j][h] = (f32x4){0.f, 0.f, 0.f, 0.f};

    // ---- prologue: stage k-step 0 into buf 0 ----
    {
        float v[16];
#pragma unroll
        for (int j = 0; j < 8; j++) v[j]     = xS[(size_t)j * NHW];
#pragma unroll
        for (int j = 0; j < 8; j++) v[8 + j] = xS[(size_t)(32 + j) * NHW];
        gload_lds16(aS, lds + aDst);
        gload_lds16(aS + 32 * NC, lds + 4096 + aDst);
        int4 q0 = { (int)pack2bf(v[0], v[1]),  (int)pack2bf(v[2], v[3]),
                    (int)pack2bf(v[4], v[5]),  (int)pack2bf(v[6], v[7]) };
        int4 q1 = { (int)pack2bf(v[8], v[9]),  (int)pack2bf(v[10], v[11]),
                    (int)pack2bf(v[12], v[13]), (int)pack2bf(v[14], v[15]) };
        *(int4*)(lds + xW0) = q0;
        *(int4*)(lds + xW1) = q1;
    }
    __syncthreads();

    const int aB = (cw * 32 + m16) * 128;   // M frag row base (cn adds 2048)
    const int xB = (pw * 32 + m16) * 128;   // X frag row base (pm adds 2048)
    const int rs = m16 & 7;

    for (int t = 0; t < NITER; t++) {
        const int cb = t & 1;
        const unsigned char* Ac = lds + cb * ABUF;
        const unsigned char* Xc = lds + XLDS + cb * XBUF;

        // depth-1 prefetch: X to regs, A via async gload into the other buffer
        float v[16];
        if (t + 1 < NITER) {
            const int k1 = (t + 1) * BK;
#pragma unroll
            for (int j = 0; j < 8; j++) v[j]     = xS[(size_t)(k1 + j) * NHW];
#pragma unroll
            for (int j = 0; j < 8; j++) v[8 + j] = xS[(size_t)(k1 + 32 + j) * NHW];
            gload_lds16(aS + k1, lds + (cb ^ 1) * ABUF + aDst);
            gload_lds16(aS + 32 * NC + k1, lds + (cb ^ 1) * ABUF + 4096 + aDst);
        }

#pragma unroll
        for (int kk = 0; kk < 2; kk++) {
            const int so = (((kk * 4 + quad) ^ rs) << 4);
            bf16x8 xf0 = *(const bf16x8*)(Xc + xB + so);            // A-operand: X[p][k]
            bf16x8 xf1 = *(const bf16x8*)(Xc + xB + 2048 + so);
            bf16x8 mf0 = *(const bf16x8*)(Ac + aB + so);            // B-operand: M[c][k]
            bf16x8 mf1 = *(const bf16x8*)(Ac + aB + 2048 + so);
            bf16x8 mn0 = flip_odd(mf0);                             // mirror rows
            bf16x8 mn1 = flip_odd(mf1);
            acc[0][0][0] = __builtin_amdgcn_mfma_f32_16x16x32_bf16(xf0, mf0, acc[0][0][0], 0, 0, 0);
            acc[0][1][0] = __builtin_amdgcn_mfma_f32_16x16x32_bf16(xf0, mf1, acc[0][1][0], 0, 0, 0);
            acc[1][0][0] = __builtin_amdgcn_mfma_f32_16x16x32_bf16(xf1, mf0, acc[1][0][0], 0, 0, 0);
            acc[1][1][0] = __builtin_amdgcn_mfma_f32_16x16x32_bf16(xf1, mf1, acc[1][1][0], 0, 0, 0);
            acc[0][0][1] = __builtin_amdgcn_mfma_f32_16x16x32_bf16(xf0, mn0, acc[0][0][1], 0, 0, 0);
            acc[0][1][1] = __builtin_amdgcn_mfma_f32_16x16x32_bf16(xf0, mn1, acc[0][1][1], 0, 0, 0);
            acc[1][0][1] = __builtin_amdgcn_mfma_f32_16x16x32_bf16(xf1, mn0, acc[1][0][1], 0, 0, 0);
            acc[1][1][1] = __builtin_amdgcn_mfma_f32_16x16x32_bf16(xf1, mn1, acc[1][1][1], 0, 0, 0);
        }

        if (t + 1 < NITER) {
            int4 q0 = { (int)pack2bf(v[0], v[1]),  (int)pack2bf(v[2], v[3]),
                        (int)pack2bf(v[4], v[5]),  (int)pack2bf(v[6], v[7]) };
            int4 q1 = { (int)pack2bf(v[8], v[9]),  (int)pack2bf(v[10], v[11]),
                        (int)pack2bf(v[12], v[13]), (int)pack2bf(v[14], v[15]) };
            *(int4*)(lds + (cb ^ 1) * XBUF + xW0) = q0;
            *(int4*)(lds + (cb ^ 1) * XBUF + xW1) = q1;
            __syncthreads();
        }
    }

    // ---- epilogue (swapped D): lane reg j = D[p = pBase+quad*4+j][c = cBase+m16]
    //      -> one dwordx4 per (pm,cn,h): 16-B contiguous in p. ----
#pragma unroll
    for (int cn = 0; cn < 2; cn++) {
        const int cLoc = ct * 64 + cw * 32 + cn * 16 + m16;   // stored-c row
#pragma unroll
        for (int pm = 0; pm < 2; pm++) {
            const int pp = pw * 32 + pm * 16 + quad * 4;
            *(f32x4*)(Ob + (size_t)cLoc * NHW + pp)         = acc[pm][cn][0];
            *(f32x4*)(Ob + (size_t)(255 - cLoc) * NHW + pp) = acc[pm][cn][1];
        }
    }
}

extern "C" void kernel_launch(void* const* d_in, const int* in_sizes, int n_in,
                              void* d_out, int out_size, void* d_ws, size_t ws_size,
                              hipStream_t stream) {
    const float* ip = (const float*)d_in[0];
    float* out = (float*)d_out;
    unsigned short* coef = (unsigned short*)d_ws;   // 128*256*2 = 64 KB of scratch

    // must redo every launch: d_ws is re-poisoned before each timed call
    coef_kernel<<<dim3(128), dim3(256), 0, stream>>>(coef);

    // 4096 blocks = 8 batches x 2 c-tiles x 256 p-tiles, XCD-swizzled in-kernel.
    dct_gemm<<<dim3(4096), dim3(256), 0, stream>>>(ip, coef, out);
}